// Round 1
// 646.301 us; speedup vs baseline: 1.0157x; 1.0157x over previous
//
#include <hip/hip_runtime.h>

// segment_sum: out[receivers[e], :] += edges[e, :]
// E=1,600,000 edges, D_EDGE=50, N_NODES=100,000, fp32.
//
// R6 theory: the two atomic phases (hist, scatter_ids) dominate (~190us each)
// because 1.6M device-scope atomics hit a 400KB array = 256 atomics per 64B
// line, serializing at the memory-side coherence point. Fix: 8-way replicated
// counters/cursors (replica = blockIdx & 7) -> 8x fewer same-line collisions.
// Scatter positions stay exact: cur[rep][r] = off[r] + sum_{q<rep} cnt[q][r],
// and hist/scatter use the IDENTICAL grid + edge->block mapping so counts
// match cursors per (rep,node).
// Gather: per-lane edge-id preload + __shfl broadcast (kills the uniform
// id-load latency chain), 16 row loads in flight (Poisson(16) degree -> one
// round trip typical). deg>64 tail uses the old uniform-load loop (P~0).

#define N_EDGES   1600000
#define D_EDGE    50
#define N_NODES   100000
#define NREP      8

// ws layout (bytes)
#define CNT_OFF   0u                  // 8 * 100000 ints = 3,200,000 B (cleared)
#define CUR_OFF   3200000u            // 8 * 100000 ints (written by make_cursors)
#define OFF_OFF   6400000u            // 100000 ints (final exclusive starts)
#define BSUM_OFF  6800000u            // 128 ints
#define EIDS_OFF  6800512u            // 1,600,000 ints
#define WS_NEEDED (6800512u + 6400000u)

__device__ __forceinline__ int clamp_node(int r) {
    return (r < 0) ? 0 : ((r >= N_NODES) ? N_NODES - 1 : r);
}

// ---------------- phase A: histogram (8-way replicated, 4 edges/thread) -----
__global__ __launch_bounds__(256) void hist_kernel(
    const int* __restrict__ receivers, int* __restrict__ cnt)
{
    int idx = blockIdx.x * 256 + threadIdx.x;
    if (idx * 4 >= N_EDGES) return;
    int4 rv = ((const int4*)receivers)[idx];
    int* c = cnt + (blockIdx.x & (NREP - 1)) * N_NODES;
    atomicAdd(&c[clamp_node(rv.x)], 1);
    atomicAdd(&c[clamp_node(rv.y)], 1);
    atomicAdd(&c[clamp_node(rv.z)], 1);
    atomicAdd(&c[clamp_node(rv.w)], 1);
}

// ---------------- phase B1: per-block scan of node TOTALS (1024/block) ------
__global__ __launch_bounds__(256) void scan_blocks_kernel(
    const int* __restrict__ cnt, int* __restrict__ off, int* __restrict__ bsum)
{
    __shared__ int s[256];
    int t = threadIdx.x;
    int base = blockIdx.x * 1024 + t * 4;
    int v0 = 0, v1 = 0, v2 = 0, v3 = 0;
    #pragma unroll
    for (int rep = 0; rep < NREP; ++rep) {
        const int* c = cnt + rep * N_NODES;
        if (base + 0 < N_NODES) v0 += c[base + 0];
        if (base + 1 < N_NODES) v1 += c[base + 1];
        if (base + 2 < N_NODES) v2 += c[base + 2];
        if (base + 3 < N_NODES) v3 += c[base + 3];
    }
    int tsum = v0 + v1 + v2 + v3;
    s[t] = tsum;
    __syncthreads();
    for (int ofs = 1; ofs < 256; ofs <<= 1) {
        int x = (t >= ofs) ? s[t - ofs] : 0;
        __syncthreads();
        s[t] += x;
        __syncthreads();
    }
    int excl = s[t] - tsum;
    if (base + 0 < N_NODES) off[base + 0] = excl;
    if (base + 1 < N_NODES) off[base + 1] = excl + v0;
    if (base + 2 < N_NODES) off[base + 2] = excl + v0 + v1;
    if (base + 3 < N_NODES) off[base + 3] = excl + v0 + v1 + v2;
    if (t == 255) bsum[blockIdx.x] = s[255];
}

// ---------------- phase B2: exclusive-scan the 98 block sums ----------------
__global__ __launch_bounds__(128) void scan_bsum_kernel(int* __restrict__ bsum, int n)
{
    __shared__ int s[128];
    int t = threadIdx.x;
    int v = (t < n) ? bsum[t] : 0;
    s[t] = v;
    __syncthreads();
    for (int ofs = 1; ofs < 128; ofs <<= 1) {
        int x = (t >= ofs) ? s[t - ofs] : 0;
        __syncthreads();
        s[t] += x;
        __syncthreads();
    }
    if (t < n) bsum[t] = s[t] - v;   // exclusive
}

// ---------------- phase B3: finalize off[] + build per-(rep,node) cursors ---
__global__ __launch_bounds__(256) void make_cursors_kernel(
    int* __restrict__ off, const int* __restrict__ bsum,
    const int* __restrict__ cnt, int* __restrict__ cur)
{
    int r = blockIdx.x * 256 + threadIdx.x;
    if (r >= N_NODES) return;
    int o = off[r] + bsum[r >> 10];
    off[r] = o;                       // final exclusive start
    int run = o;
    #pragma unroll
    for (int rep = 0; rep < NREP; ++rep) {
        cur[rep * N_NODES + r] = run;
        run += cnt[rep * N_NODES + r];
    }
}

// ---------------- phase C: scatter edge ids (replicated cursors) ------------
// MUST mirror hist_kernel's grid + edge->block mapping so rep matches.
__global__ __launch_bounds__(256) void scatter_ids_kernel(
    const int* __restrict__ receivers, int* __restrict__ cur, int* __restrict__ eids)
{
    int idx = blockIdx.x * 256 + threadIdx.x;
    if (idx * 4 >= N_EDGES) return;
    int4 rv = ((const int4*)receivers)[idx];
    int* c = cur + (blockIdx.x & (NREP - 1)) * N_NODES;
    int e = idx * 4;
    int p;
    p = atomicAdd(&c[clamp_node(rv.x)], 1); if (p >= 0 && p < N_EDGES) eids[p] = e + 0;
    p = atomicAdd(&c[clamp_node(rv.y)], 1); if (p >= 0 && p < N_EDGES) eids[p] = e + 1;
    p = atomicAdd(&c[clamp_node(rv.z)], 1); if (p >= 0 && p < N_EDGES) eids[p] = e + 2;
    p = atomicAdd(&c[clamp_node(rv.w)], 1); if (p >= 0 && p < N_EDGES) eids[p] = e + 3;
}

// ---------------- phase D: gather-sum, one wave per node --------------------
// Per-lane eid preload + shfl broadcast; 16 independent row loads in flight.
__global__ __launch_bounds__(256) void gather_kernel(
    const float* __restrict__ edges, const int* __restrict__ off,
    const int* __restrict__ eids, float* __restrict__ out)
{
    int node = blockIdx.x * 4 + (threadIdx.x >> 6);
    int lane = threadIdx.x & 63;
    if (node >= N_NODES) return;

    int start = off[node];
    int end   = (node == N_NODES - 1) ? N_EDGES : off[node + 1];
    start = (start < 0) ? 0 : start;
    end   = (end > N_EDGES) ? N_EDGES : end;
    int l = (lane < D_EDGE) ? lane : 0;    // inactive lanes alias lane 0
    int deg = end - start;
    if (deg <= 0) {
        if (lane < D_EDGE) out[node * D_EDGE + lane] = 0.0f;
        return;
    }
    int last = end - 1;

    // one per-lane load covers the whole node for deg<=64 (P(deg>64)~1e-20)
    int idx = start + lane;
    idx = (idx <= last) ? idx : last;
    int eid = eids[idx];
    eid = (eid < 0 || eid >= N_EDGES) ? 0 : eid;

    float acc = 0.0f;
    int dcap = (deg < 64) ? deg : 64;

#define G16(k) \
    int   e##k = __shfl(eid, j + k); \
    float m##k = (j + k < deg) ? 1.0f : 0.0f; \
    float a##k = edges[e##k * D_EDGE + l];

    for (int j = 0; j < dcap; j += 16) {
        G16(0)  G16(1)  G16(2)  G16(3)
        G16(4)  G16(5)  G16(6)  G16(7)
        G16(8)  G16(9)  G16(10) G16(11)
        G16(12) G16(13) G16(14) G16(15)
        acc += (((a0 + m1 * a1) + (m2 * a2 + m3 * a3))
              + ((m4 * a4 + m5 * a5) + (m6 * a6 + m7 * a7)))
             + (((m8 * a8 + m9 * a9) + (m10 * a10 + m11 * a11))
              + ((m12 * a12 + m13 * a13) + (m14 * a14 + m15 * a15)));
    }
#undef G16

    // rare tail: deg > 64, uniform-load 8-wide masked loop
    for (int j = start + 64; j < end; j += 8) {
        int i0 = j + 0, i1 = j + 1, i2 = j + 2, i3 = j + 3;
        int i4 = j + 4, i5 = j + 5, i6 = j + 6, i7 = j + 7;
        float m1 = (i1 <= last) ? 1.0f : 0.0f;
        float m2 = (i2 <= last) ? 1.0f : 0.0f;
        float m3 = (i3 <= last) ? 1.0f : 0.0f;
        float m4 = (i4 <= last) ? 1.0f : 0.0f;
        float m5 = (i5 <= last) ? 1.0f : 0.0f;
        float m6 = (i6 <= last) ? 1.0f : 0.0f;
        float m7 = (i7 <= last) ? 1.0f : 0.0f;
        i1 = (i1 <= last) ? i1 : last;
        i2 = (i2 <= last) ? i2 : last;
        i3 = (i3 <= last) ? i3 : last;
        i4 = (i4 <= last) ? i4 : last;
        i5 = (i5 <= last) ? i5 : last;
        i6 = (i6 <= last) ? i6 : last;
        i7 = (i7 <= last) ? i7 : last;
        int e0 = eids[i0], e1 = eids[i1], e2 = eids[i2], e3 = eids[i3];
        int e4 = eids[i4], e5 = eids[i5], e6 = eids[i6], e7 = eids[i7];
        e0 = (e0 < 0 || e0 >= N_EDGES) ? 0 : e0;
        e1 = (e1 < 0 || e1 >= N_EDGES) ? 0 : e1;
        e2 = (e2 < 0 || e2 >= N_EDGES) ? 0 : e2;
        e3 = (e3 < 0 || e3 >= N_EDGES) ? 0 : e3;
        e4 = (e4 < 0 || e4 >= N_EDGES) ? 0 : e4;
        e5 = (e5 < 0 || e5 >= N_EDGES) ? 0 : e5;
        e6 = (e6 < 0 || e6 >= N_EDGES) ? 0 : e6;
        e7 = (e7 < 0 || e7 >= N_EDGES) ? 0 : e7;
        float a0 = edges[e0 * D_EDGE + l];
        float a1 = edges[e1 * D_EDGE + l];
        float a2 = edges[e2 * D_EDGE + l];
        float a3 = edges[e3 * D_EDGE + l];
        float a4 = edges[e4 * D_EDGE + l];
        float a5 = edges[e5 * D_EDGE + l];
        float a6 = edges[e6 * D_EDGE + l];
        float a7 = edges[e7 * D_EDGE + l];
        acc += ((a0 + m1 * a1) + (m2 * a2 + m3 * a3))
             + ((m4 * a4 + m5 * a5) + (m6 * a6 + m7 * a7));
    }

    if (lane < D_EDGE) out[node * D_EDGE + lane] = acc;
}

// ---------------- fallback (R1): element-wise atomics ----------------
__global__ __launch_bounds__(256) void scatter_add_kernel(
    const float* __restrict__ edges, const int* __restrict__ receivers,
    float* __restrict__ out)
{
    long long t = (long long)blockIdx.x * blockDim.x + threadIdx.x;
    if (t >= (long long)N_EDGES * D_EDGE) return;
    int e = (int)(t / D_EDGE);
    int d = (int)(t - (long long)e * D_EDGE);
    int r = receivers[e];
    r = clamp_node(r);
    atomicAdd(&out[(long long)r * D_EDGE + d], edges[t]);
}

extern "C" void kernel_launch(void* const* d_in, const int* in_sizes, int n_in,
                              void* d_out, int out_size, void* d_ws, size_t ws_size,
                              hipStream_t stream) {
    const float* edges     = (const float*)d_in[1];
    const int*   receivers = (const int*)d_in[2];
    float*       out       = (float*)d_out;

    if (ws_size < WS_NEEDED || d_ws == nullptr) {
        hipMemsetAsync(d_out, 0, (size_t)out_size * sizeof(float), stream);
        const long long total = (long long)N_EDGES * D_EDGE;
        const int grid = (int)((total + 255) / 256);
        scatter_add_kernel<<<grid, 256, 0, stream>>>(edges, receivers, out);
        return;
    }

    char* ws   = (char*)d_ws;
    int*  cnt  = (int*)(ws + CNT_OFF);
    int*  cur  = (int*)(ws + CUR_OFF);
    int*  off  = (int*)(ws + OFF_OFF);
    int*  bsum = (int*)(ws + BSUM_OFF);
    int*  eids = (int*)(ws + EIDS_OFF);

    hipMemsetAsync(cnt, 0, (size_t)NREP * N_NODES * sizeof(int), stream);

    const int egrid4 = (N_EDGES / 4 + 255) / 256;            // 1563 blocks, 4 edges/thread
    hist_kernel<<<egrid4, 256, 0, stream>>>(receivers, cnt);

    const int sblocks = (N_NODES + 1023) / 1024;             // 98
    scan_blocks_kernel<<<sblocks, 256, 0, stream>>>(cnt, off, bsum);
    scan_bsum_kernel<<<1, 128, 0, stream>>>(bsum, sblocks);
    make_cursors_kernel<<<(N_NODES + 255) / 256, 256, 0, stream>>>(off, bsum, cnt, cur);

    scatter_ids_kernel<<<egrid4, 256, 0, stream>>>(receivers, cur, eids);

    gather_kernel<<<(N_NODES + 3) / 4, 256, 0, stream>>>(edges, off, eids, out);
}